// Round 6
// baseline (164.523 us; speedup 1.0000x reference)
//
#include <hip/hip_runtime.h>
#include <cstdint>

// B=16384 rows, K=2048 centers, D=128, T=1.0
// Outputs (flat, f32): out[B*D], center[K*D], label[B]
#define NB 16384
#define NK 2048
#define ND 128
#define MARGIN 0.10f
#define CAP 6144
#define XPITCH 132   // padded LDS x-row stride (floats): breaks bank aliasing

typedef __attribute__((ext_vector_type(8))) short bf16x8;
typedef __attribute__((ext_vector_type(4))) float f32x4;
typedef unsigned long long u64;

__device__ __forceinline__ unsigned short f2bf(float f) {
    unsigned u = __float_as_uint(f);
    u += 0x7fffu + ((u >> 16) & 1u);          // round-to-nearest-even
    return (unsigned short)(u >> 16);
}

// ---------------------------------------------------------------------------
// Prep (392 blocks):
//  [0,128)    cbf: center -> bf16 MFMA B-frag layout
//  [128,136)  c2 (chain identical to R1)
//  [136,392)  center passthrough copy (float4)
// ---------------------------------------------------------------------------
__global__ __launch_bounds__(256)
void prep(const float* __restrict__ c,
          unsigned short* __restrict__ cbf,
          float* __restrict__ c2,
          float* __restrict__ out_center) {
    const int bid = blockIdx.x;
    const int tid = threadIdx.x;
    if (bid < 128) {
        int t = bid * 256 + tid;              // 0..32767
        int lane = t & 63, s = (t >> 6) & 3, kt = t >> 8;
        int kc = kt * 16 + (lane & 15);
        int d0 = s * 32 + (lane >> 4) * 8;
        const float* src = c + (long)kc * ND + d0;
        unsigned short h[8];
#pragma unroll
        for (int j = 0; j < 8; ++j) h[j] = f2bf(src[j]);
        int4 pk;
        pk.x = h[0] | (h[1] << 16); pk.y = h[2] | (h[3] << 16);
        pk.z = h[4] | (h[5] << 16); pk.w = h[6] | (h[7] << 16);
        ((int4*)cbf)[t] = pk;
    } else if (bid < 136) {
        int k = (bid - 128) * 256 + tid;      // 0..2047
        const float4* row = (const float4*)(c + (long)k * ND);
        float s = 0.f;
#pragma unroll 8
        for (int i = 0; i < ND / 4; ++i) {
            float4 v = row[i];
            s += v.x * v.x + v.y * v.y + v.z * v.z + v.w * v.w;
        }
        c2[k] = s;
    } else {
        int i = (bid - 136) * 256 + tid;      // 0..K*D/4-1
        ((float4*)out_center)[i] = ((const float4*)c)[i];
    }
}

// ---------------------------------------------------------------------------
// Main: 512 blocks x 512 threads (8 waves). Block owns 32 rows x ALL 2048 k.
// Wave w covers k in [w*256, w*256+256). SINGLE MFMA sweep: per 16-k tile,
// compute d2, 4-level shfl row-reduce -> running rowmin, and collect any
// d2 <= rowmin + MARGIN into the candidate list. Since rowmin only
// decreases, the collected set is a SUPERSET of {d2 <= final_min + MARGIN};
// bf16 error (~2e-3 RMS) << MARGIN/2 guarantees the exact argmin is always
// collected. The unchanged exact fp32 refine prunes the extra junk ->
// output bit-identical to the two-sweep version, at HALF the cbf L2
// traffic and HALF the MFMA work.
//
// History:
//  R1: 32 rows, (256,2): 49 us -- 2 w/SIMD latency-bound.
//  R2: (1024,8): forced <=64 VGPR, spilled, 131 us.
//  R3: 32 rows, (512,4): ~38 us. 4 w/SIMD.
//  R4: +prefetch, c2->LDS: NEUTRAL (latency covered at 4 w/SIMD).
//  R5: 64 rows = 256 blocks = 1 block/CU -> 2 w/SIMD: 43.5 us REGRESSION.
//      => concurrency-limited; lever = bytes/MFMA per k, not rows/block.
//  R6: single-sweep running-threshold collection (this version).
// ---------------------------------------------------------------------------
__global__ __launch_bounds__(512, 4)
void kmeans_main(const float* __restrict__ x,
                 const float* __restrict__ center,
                 const unsigned short* __restrict__ cbf,
                 const float* __restrict__ c2,
                 float* __restrict__ out,
                 float* __restrict__ label_out) {
    __shared__ float xs[32 * XPITCH];         // 16.9 KB fp32 x rows
    __shared__ float c2s[NK];                 // 8 KB center norms
    __shared__ float x2s[32];
    __shared__ u64 best[32];
    __shared__ unsigned buf[CAP];             // 24 KB candidate list
    __shared__ unsigned cnt;

    const int tid  = threadIdx.x;
    const int lane = tid & 63;
    const int wave = __builtin_amdgcn_readfirstlane(tid >> 6);  // 0..7
    const long rb  = (long)blockIdx.x * 32;

    // ---- stage x rows -> LDS (coalesced, 2 float4/thread) ----
    {
        int idx = tid;                        // float4 index 0..1023
        int r = idx >> 5, q = idx & 31;
        ((float4*)(xs + r * XPITCH))[q] = ((const float4*)(x + (rb + r) * ND))[q];
        idx = tid + 512;
        r = idx >> 5; q = idx & 31;
        ((float4*)(xs + r * XPITCH))[q] = ((const float4*)(x + (rb + r) * ND))[q];
    }
    // ---- stage c2 -> LDS (4 floats/thread, coalesced) ----
    ((float4*)c2s)[tid] = ((const float4*)c2)[tid];
    if (tid < 32) best[tid] = ~0ULL;
    if (tid == 0) cnt = 0;
    __syncthreads();

    // ---- x2 per row: chain IDENTICAL to R1 (float2, 6-level butterfly) ----
    for (int i = 0; i < 4; ++i) {
        int r = wave * 4 + i;
        float2 v = *(const float2*)(xs + r * XPITCH + lane * 2);
        float s = v.x * v.x + v.y * v.y;
#pragma unroll
        for (int off = 32; off; off >>= 1) s += __shfl_xor(s, off, 64);
        if (lane == 0) x2s[r] = s;
    }
    __syncthreads();

    // ---- A-frags into registers ----
    bf16x8 af[2][4];
#pragma unroll
    for (int rt = 0; rt < 2; ++rt)
#pragma unroll
        for (int s = 0; s < 4; ++s) {
            const float* p = xs + (rt * 16 + (lane & 15)) * XPITCH
                               + s * 32 + (lane >> 4) * 8;
            float4 u0 = ((const float4*)p)[0];
            float4 u1 = ((const float4*)p)[1];
            bf16x8 a;
            a[0] = (short)f2bf(u0.x); a[1] = (short)f2bf(u0.y);
            a[2] = (short)f2bf(u0.z); a[3] = (short)f2bf(u0.w);
            a[4] = (short)f2bf(u1.x); a[5] = (short)f2bf(u1.y);
            a[6] = (short)f2bf(u1.z); a[7] = (short)f2bf(u1.w);
            af[rt][s] = a;
        }

    float x2p[2][4];
#pragma unroll
    for (int rt = 0; rt < 2; ++rt)
#pragma unroll
        for (int reg = 0; reg < 4; ++reg)
            x2p[rt][reg] = x2s[rt * 16 + (lane >> 4) * 4 + reg];

    const bf16x8* CF = (const bf16x8*)cbf;
    const int kt0 = wave * 16;                // 16-k tile index base

    // ---- single sweep: min + collect with running row-min threshold ----
    float rowmin[2][4];
#pragma unroll
    for (int rt = 0; rt < 2; ++rt)
#pragma unroll
        for (int reg = 0; reg < 4; ++reg) rowmin[rt][reg] = __builtin_inff();

#pragma unroll 1
    for (int ct = 0; ct < 16; ++ct) {
        const int kt = kt0 + ct;
        bf16x8 bf[4];
#pragma unroll
        for (int s = 0; s < 4; ++s) bf[s] = CF[(kt * 4 + s) * 64 + lane];
        f32x4 acc0 = {0.f,0.f,0.f,0.f}, acc1 = {0.f,0.f,0.f,0.f};
#pragma unroll
        for (int s = 0; s < 4; ++s) {
            acc0 = __builtin_amdgcn_mfma_f32_16x16x32_bf16(af[0][s], bf[s], acc0, 0,0,0);
            acc1 = __builtin_amdgcn_mfma_f32_16x16x32_bf16(af[1][s], bf[s], acc1, 0,0,0);
        }
        float c2v = c2s[kt * 16 + (lane & 15)];
        const int col = kt * 16 + (lane & 15);
#pragma unroll
        for (int reg = 0; reg < 4; ++reg) {
            float d20 = fmaf(-2.f, acc0[reg], x2p[0][reg] + c2v);
            float d21 = fmaf(-2.f, acc1[reg], x2p[1][reg] + c2v);
            // row min of this tile (16 col-lanes share a row)
            float m0 = d20, m1 = d21;
#pragma unroll
            for (int off = 1; off < 16; off <<= 1) {
                m0 = fminf(m0, __shfl_xor(m0, off, 64));
                m1 = fminf(m1, __shfl_xor(m1, off, 64));
            }
            rowmin[0][reg] = fminf(rowmin[0][reg], m0);
            rowmin[1][reg] = fminf(rowmin[1][reg], m1);
            if (d20 <= rowmin[0][reg] + MARGIN) {
                unsigned rloc = (lane >> 4) * 4 + reg;          // rt=0
                unsigned idx = atomicAdd(&cnt, 1u);
                if (idx < CAP) buf[idx] = (rloc << 11) | (unsigned)col;
            }
            if (d21 <= rowmin[1][reg] + MARGIN) {
                unsigned rloc = 16 + (lane >> 4) * 4 + reg;     // rt=1
                unsigned idx = atomicAdd(&cnt, 1u);
                if (idx < CAP) buf[idx] = (rloc << 11) | (unsigned)col;
            }
        }
    }
    __syncthreads();

    // ---- exact refine: fp32 chain IDENTICAL to R1 (serial fmaf dot,
    //      t=x2+c2, fmaf(-2,dot,t), max, sqrt; u64 key -> lowest k on tie) ----
    unsigned n = cnt; if (n > CAP) n = CAP;
    for (unsigned i = tid; i < n; i += 512) {
        unsigned pc = buf[i];
        int rloc = pc >> 11, col = pc & (NK - 1);
        const float* xr = xs + rloc * XPITCH;
        const float* cr = center + (long)col * ND;
        float dot = 0.f;
#pragma unroll 8
        for (int d = 0; d < ND; ++d) dot = fmaf(xr[d], cr[d], dot);
        float t = x2s[rloc] + c2s[col];
        float f = fmaxf(fmaf(-2.0f, dot, t), 0.0f);
        float s = __builtin_sqrtf(f);
        u64 key = ((u64)__float_as_uint(s) << 32) | (unsigned)col;
        atomicMin(&best[rloc], key);
    }
    __syncthreads();

    // ---- direct output: gather center[bk] per row + label ----
    for (int i = 0; i < 4; ++i) {
        int rloc = wave * 4 + i;
        int bk = (int)(best[rloc] & 0xffffffffULL);
        float2 cv = ((const float2*)(center + (long)bk * ND))[lane];
        ((float2*)(out + (rb + rloc) * ND))[lane] = cv;
        if (lane == 0) label_out[rb + rloc] = (float)bk;
    }
}

// ---------------------------------------------------------------------------
extern "C" void kernel_launch(void* const* d_in, const int* in_sizes, int n_in,
                              void* d_out, int out_size, void* d_ws, size_t ws_size,
                              hipStream_t stream) {
    const float* x      = (const float*)d_in[0];   // [B][D]
    const float* center = (const float*)d_in[1];   // [K][D]
    float* out = (float*)d_out;

    float* out_x      = out;                        // [B*D]
    float* out_center = out + (long)NB * ND;        // [K*D]
    float* out_label  = out_center + (long)NK * ND; // [B]

    // Workspace: cbf[K*D]u16 (0.5MB), c2[K]f32
    unsigned short* cbf = (unsigned short*)d_ws;
    float* c2 = (float*)(cbf + (size_t)NK * ND);

    prep<<<392, 256, 0, stream>>>(center, cbf, c2, out_center);
    kmeans_main<<<NB / 32, 512, 0, stream>>>(x, center, cbf, c2,
                                             out_x, out_label);
}

// Round 9
// 100.693 us; speedup vs baseline: 1.6339x; 1.6339x over previous
//
#include <hip/hip_runtime.h>
#include <cstdint>

// B=16384 rows, K=2048 centers, D=128, T=1.0
// Outputs (flat, f32): out[B*D], center[K*D], label[B]
#define NB 16384
#define NK 2048
#define ND 128
#define WMARG 0.10f      // collect window: >= 2*eps_bf16 (0.031) + quant slack (0.031)
#define CAP 2048
#define XPITCH 132       // padded LDS x-row stride (floats)
#define CPITCH 1036      // u8-cache row pitch in dwords (1024 + 12: staggers banks)

typedef __attribute__((ext_vector_type(8))) short bf16x8;
typedef __attribute__((ext_vector_type(4))) float f32x4;
typedef unsigned long long u64;

__device__ __forceinline__ unsigned short f2bf(float f) {
    unsigned u = __float_as_uint(f);
    u += 0x7fffu + ((u >> 16) & 1u);          // round-to-nearest-even
    return (unsigned short)(u >> 16);
}

// ---------------------------------------------------------------------------
// Prep (392 blocks): cbf B-frag layout | c2 (R1-identical chain) | center copy
// ---------------------------------------------------------------------------
__global__ __launch_bounds__(256)
void prep(const float* __restrict__ c,
          unsigned short* __restrict__ cbf,
          float* __restrict__ c2,
          float* __restrict__ out_center) {
    const int bid = blockIdx.x;
    const int tid = threadIdx.x;
    if (bid < 128) {
        int t = bid * 256 + tid;              // 0..32767
        int lane = t & 63, s = (t >> 6) & 3, kt = t >> 8;
        int kc = kt * 16 + (lane & 15);
        int d0 = s * 32 + (lane >> 4) * 8;
        const float* src = c + (long)kc * ND + d0;
        unsigned short h[8];
#pragma unroll
        for (int j = 0; j < 8; ++j) h[j] = f2bf(src[j]);
        int4 pk;
        pk.x = h[0] | (h[1] << 16); pk.y = h[2] | (h[3] << 16);
        pk.z = h[4] | (h[5] << 16); pk.w = h[6] | (h[7] << 16);
        ((int4*)cbf)[t] = pk;
    } else if (bid < 136) {
        int k = (bid - 128) * 256 + tid;      // 0..2047
        const float4* row = (const float4*)(c + (long)k * ND);
        float s = 0.f;
#pragma unroll 8
        for (int i = 0; i < ND / 4; ++i) {
            float4 v = row[i];
            s += v.x * v.x + v.y * v.y + v.z * v.z + v.w * v.w;
        }
        c2[k] = s;
    } else {
        int i = (bid - 136) * 256 + tid;      // 0..K*D/4-1
        ((float4*)out_center)[i] = ((const float4*)c)[i];
    }
}

// ---------------------------------------------------------------------------
// Main: 512 blocks x 512 threads (8 waves). Block owns 32 rows x ALL 2048 k.
// SINGLE MFMA sweep in 2 chunks of 1024 k. Per tile: d2 -> per-lane running
// min (pure VALU) + u8-quantized residual r=d2-x2row cached in LDS (packed
// 4 rows/dword). After each chunk: block-reduce mins -> bmin (shfls OUTSIDE
// the loop, R6 lesson), integer per-row threshold, cheap LDS scan collects
// ~150 tight candidates. Exact fp32 refine chain (R1-identical) + output.
//
// Correctness: q monotone (trunc both sides); collect iff q <= qthr where
// qthr = trunc(f(m - x2row + WMARG)), f(r)=r*31.875+128. For argmin k*:
// r* <= (m - x2row) + 2*eps, and f(thr)-f(r*) >= (WMARG-2eps)*31.875 >= 2.2
// > 1 -> always collected. Low-clamp (q==0) always collects. Refine exact.
//
// History: R1 49us | R2 spill 131us | R3 two-sweep 38us | R4 neutral |
// R5 1 blk/CU regress | R6 shfl-in-loop regress (DS-bound) | R8 per-lane
// loose collect: CAP overflow -> WRONG + refine-cost analysis shows loose
// collection unviable. R9: tight-threshold via u8 d2-cache (this).
// ---------------------------------------------------------------------------
__global__ __launch_bounds__(512, 4)
void kmeans_main(const float* __restrict__ x,
                 const float* __restrict__ center,
                 const unsigned short* __restrict__ cbf,
                 const float* __restrict__ c2,
                 float* __restrict__ out,
                 float* __restrict__ label_out) {
    __shared__ float xs[32 * XPITCH];          // 16.9 KB x rows (fp32)
    __shared__ float c2s[NK];                  // 8 KB center norms
    __shared__ unsigned cacheu[8 * CPITCH];    // 33.2 KB u8 d2-residual cache
    __shared__ float x2s[32];
    __shared__ unsigned bmin[32];
    __shared__ unsigned char qthr[32];
    __shared__ u64 best[32];
    __shared__ unsigned short buf[CAP];        // 4 KB candidate list
    __shared__ unsigned cnt;

    const int tid  = threadIdx.x;
    const int lane = tid & 63;
    const int wave = __builtin_amdgcn_readfirstlane(tid >> 6);  // 0..7
    const long rb  = (long)blockIdx.x * 32;

    // ---- stage x rows -> LDS (coalesced, 2 float4/thread) ----
    {
        int idx = tid;
        int r = idx >> 5, q = idx & 31;
        ((float4*)(xs + r * XPITCH))[q] = ((const float4*)(x + (rb + r) * ND))[q];
        idx = tid + 512;
        r = idx >> 5; q = idx & 31;
        ((float4*)(xs + r * XPITCH))[q] = ((const float4*)(x + (rb + r) * ND))[q];
    }
    ((float4*)c2s)[tid] = ((const float4*)c2)[tid];
    if (tid < 32) { bmin[tid] = 0x7f800000u; best[tid] = ~0ULL; }
    if (tid == 0) cnt = 0;
    __syncthreads();

    // ---- x2 per row: chain IDENTICAL to R1 (float2, 6-level butterfly) ----
    for (int i = 0; i < 4; ++i) {
        int r = wave * 4 + i;
        float2 v = *(const float2*)(xs + r * XPITCH + lane * 2);
        float s = v.x * v.x + v.y * v.y;
#pragma unroll
        for (int off = 32; off; off >>= 1) s += __shfl_xor(s, off, 64);
        if (lane == 0) x2s[r] = s;
    }
    __syncthreads();

    // ---- A-frags into registers ----
    bf16x8 af[2][4];
#pragma unroll
    for (int rt = 0; rt < 2; ++rt)
#pragma unroll
        for (int s = 0; s < 4; ++s) {
            const float* p = xs + (rt * 16 + (lane & 15)) * XPITCH
                               + s * 32 + (lane >> 4) * 8;
            float4 u0 = ((const float4*)p)[0];
            float4 u1 = ((const float4*)p)[1];
            bf16x8 a;
            a[0] = (short)f2bf(u0.x); a[1] = (short)f2bf(u0.y);
            a[2] = (short)f2bf(u0.z); a[3] = (short)f2bf(u0.w);
            a[4] = (short)f2bf(u1.x); a[5] = (short)f2bf(u1.y);
            a[6] = (short)f2bf(u1.z); a[7] = (short)f2bf(u1.w);
            af[rt][s] = a;
        }

    float x2p[2][4];
#pragma unroll
    for (int rt = 0; rt < 2; ++rt)
#pragma unroll
        for (int reg = 0; reg < 4; ++reg)
            x2p[rt][reg] = x2s[rt * 16 + (lane >> 4) * 4 + reg];

    const bf16x8* CF = (const bf16x8*)cbf;
    const int quad = lane >> 4;                // 0..3 (row quad within tile)

    float rowmin[2][4];
#pragma unroll
    for (int rt = 0; rt < 2; ++rt)
#pragma unroll
        for (int reg = 0; reg < 4; ++reg) rowmin[rt][reg] = __builtin_inff();

    for (int chunk = 0; chunk < 2; ++chunk) {
        const int kt0 = wave * 16 + chunk * 8;

        // ---- MFMA sweep over this chunk's 8 tiles; cache u8 residuals ----
#pragma unroll 1
        for (int ct = 0; ct < 8; ++ct) {
            const int kt = kt0 + ct;
            bf16x8 bfr[4];
#pragma unroll
            for (int s = 0; s < 4; ++s) bfr[s] = CF[(kt * 4 + s) * 64 + lane];
            f32x4 acc0 = {0.f,0.f,0.f,0.f}, acc1 = {0.f,0.f,0.f,0.f};
#pragma unroll
            for (int s = 0; s < 4; ++s) {
                acc0 = __builtin_amdgcn_mfma_f32_16x16x32_bf16(af[0][s], bfr[s], acc0, 0,0,0);
                acc1 = __builtin_amdgcn_mfma_f32_16x16x32_bf16(af[1][s], bfr[s], acc1, 0,0,0);
            }
            float c2v = c2s[kt * 16 + (lane & 15)];
            const int kg = wave * 128 + ct * 16 + (lane & 15);  // cache k index
            unsigned pk0 = 0, pk1 = 0;
#pragma unroll
            for (int reg = 0; reg < 4; ++reg) {
                float d20 = fmaf(-2.f, acc0[reg], x2p[0][reg] + c2v);
                float d21 = fmaf(-2.f, acc1[reg], x2p[1][reg] + c2v);
                rowmin[0][reg] = fminf(rowmin[0][reg], d20);
                rowmin[1][reg] = fminf(rowmin[1][reg], d21);
                // q = round((r+4)*31.875), r = d2 - x2row; clamp [0,255]
                float q0 = fmaf(d20 - x2p[0][reg], 31.875f, 128.0f);
                float q1 = fmaf(d21 - x2p[1][reg], 31.875f, 128.0f);
                q0 = fminf(fmaxf(q0, 0.f), 255.f);
                q1 = fminf(fmaxf(q1, 0.f), 255.f);
                pk0 |= ((unsigned)q0) << (8 * reg);
                pk1 |= ((unsigned)q1) << (8 * reg);
            }
            cacheu[(0 * 4 + quad) * CPITCH + kg] = pk0;
            cacheu[(1 * 4 + quad) * CPITCH + kg] = pk1;
        }

        // ---- block-reduce running rowmin -> bmin (OUTSIDE loop) ----
#pragma unroll
        for (int rt = 0; rt < 2; ++rt)
#pragma unroll
            for (int reg = 0; reg < 4; ++reg) {
                float v = rowmin[rt][reg];
#pragma unroll
                for (int off = 1; off < 16; off <<= 1)
                    v = fminf(v, __shfl_xor(v, off, 64));
                if ((lane & 15) == 0)          // d2 ~ 128 >> 0 -> uint order ok
                    atomicMin(&bmin[rt * 16 + quad * 4 + reg], __float_as_uint(v));
            }
        __syncthreads();                       // cache writes + bmin done

        // ---- per-row integer threshold ----
        if (tid < 32) {
            float m   = __uint_as_float(bmin[tid]);
            float thr = m - x2s[tid] + WMARG;
            float qf  = fmaf(thr, 31.875f, 128.0f);
            qthr[tid] = (unsigned char)fminf(fmaxf(qf, 0.f), 255.f);
        }
        __syncthreads();                       // qthr ready

        // ---- scan cache, collect tight candidates ----
        for (int t = tid; t < 8 * 1024; t += 512) {
            int g = t >> 10, k = t & 1023;
            unsigned u = cacheu[g * CPITCH + k];
            int rbase = (g >> 2) * 16 + (g & 3) * 4;
            int col = ((k >> 7) << 8) + chunk * 128 + (k & 127);
#pragma unroll
            for (int j = 0; j < 4; ++j) {
                unsigned q = (u >> (8 * j)) & 255u;
                if (q <= (unsigned)qthr[rbase + j]) {
                    unsigned idx = atomicAdd(&cnt, 1u);
                    if (idx < CAP)
                        buf[idx] = (unsigned short)(((rbase + j) << 11) | col);
                }
            }
        }
        __syncthreads();                       // scan done before cache reuse
    }

    // ---- exact refine: fp32 chain IDENTICAL to R1 (serial fmaf dot,
    //      t=x2+c2, fmaf(-2,dot,t), max, sqrt; u64 key -> lowest k on tie) ----
    unsigned n = cnt; if (n > CAP) n = CAP;
    for (unsigned i = tid; i < n; i += 512) {
        unsigned pc = buf[i];
        int rloc = pc >> 11, col = pc & (NK - 1);
        const float* xr = xs + rloc * XPITCH;
        const float* cr = center + (long)col * ND;
        float dot = 0.f;
#pragma unroll 8
        for (int d = 0; d < ND; ++d) dot = fmaf(xr[d], cr[d], dot);
        float t = x2s[rloc] + c2s[col];
        float f = fmaxf(fmaf(-2.0f, dot, t), 0.0f);
        float s = __builtin_sqrtf(f);
        u64 key = ((u64)__float_as_uint(s) << 32) | (unsigned)col;
        atomicMin(&best[rloc], key);
    }
    __syncthreads();

    // ---- direct output: gather center[bk] per row + label ----
    for (int i = 0; i < 4; ++i) {
        int rloc = wave * 4 + i;
        int bk = (int)(best[rloc] & 0xffffffffULL);
        float2 cv = ((const float2*)(center + (long)bk * ND))[lane];
        ((float2*)(out + (rb + rloc) * ND))[lane] = cv;
        if (lane == 0) label_out[rb + rloc] = (float)bk;
    }
}

// ---------------------------------------------------------------------------
extern "C" void kernel_launch(void* const* d_in, const int* in_sizes, int n_in,
                              void* d_out, int out_size, void* d_ws, size_t ws_size,
                              hipStream_t stream) {
    const float* x      = (const float*)d_in[0];   // [B][D]
    const float* center = (const float*)d_in[1];   // [K][D]
    float* out = (float*)d_out;

    float* out_x      = out;                        // [B*D]
    float* out_center = out + (long)NB * ND;        // [K*D]
    float* out_label  = out_center + (long)NK * ND; // [B]

    // Workspace: cbf[K*D]u16 (0.5MB), c2[K]f32
    unsigned short* cbf = (unsigned short*)d_ws;
    float* c2 = (float*)(cbf + (size_t)NK * ND);

    prep<<<392, 256, 0, stream>>>(center, cbf, c2, out_center);
    kmeans_main<<<NB / 32, 512, 0, stream>>>(x, center, cbf, c2,
                                             out_x, out_label);
}